// Round 1
// baseline (1489.684 us; speedup 1.0000x reference)
//
#include <hip/hip_runtime.h>

#define B_  4
#define S_  2048
#define D_  1024
#define N_  (B_*S_)            // 8192 rows of x flattened
#define SCALE 0.03125f         // 1/sqrt(1024)
#define NEGINF (-3.0e38f)

#define BM 64
#define BN 64
#define BK 16

// ---------------- K1: Q/K/V projection (NN GEMM, z picks weight) ----------------
__global__ __launch_bounds__(256) void qkv_gemm(
    const float* __restrict__ x,  const float* __restrict__ Wq,
    const float* __restrict__ Wk, const float* __restrict__ Wv,
    float* __restrict__ Q, float* __restrict__ Kp, float* __restrict__ Vp)
{
    const float* W = (blockIdx.z == 0) ? Wq : (blockIdx.z == 1) ? Wk : Wv;
    float*     Out = (blockIdx.z == 0) ? Q  : (blockIdx.z == 1) ? Kp : Vp;
    const int row0 = blockIdx.y * BM;
    const int col0 = blockIdx.x * BN;
    __shared__ float As[BK][BM];
    __shared__ float Bs[BK][BN];
    const int tid = threadIdx.x;
    const int ar  = tid >> 2,  ac4 = (tid & 3)  << 2;   // A tile: 64 rows x 16 k
    const int bkr = tid >> 4,  bc4 = (tid & 15) << 2;   // B tile: 16 k x 64 cols
    const int tm  = (tid >> 4) << 2, tn = (tid & 15) << 2;
    float acc[4][4] = {};
    for (int k0 = 0; k0 < D_; k0 += BK) {
        float4 av = *(const float4*)&x[(size_t)(row0 + ar) * D_ + k0 + ac4];
        float4 bv = *(const float4*)&W[(size_t)(k0 + bkr) * D_ + col0 + bc4];
        __syncthreads();
        As[ac4+0][ar] = av.x; As[ac4+1][ar] = av.y; As[ac4+2][ar] = av.z; As[ac4+3][ar] = av.w;
        *(float4*)&Bs[bkr][bc4] = bv;
        __syncthreads();
#pragma unroll
        for (int kk = 0; kk < BK; ++kk) {
            float a[4], b[4];
            *(float4*)a = *(const float4*)&As[kk][tm];
            *(float4*)b = *(const float4*)&Bs[kk][tn];
#pragma unroll
            for (int i = 0; i < 4; ++i)
#pragma unroll
                for (int j = 0; j < 4; ++j) acc[i][j] = fmaf(a[i], b[j], acc[i][j]);
        }
    }
#pragma unroll
    for (int i = 0; i < 4; ++i) {
        float4 v = make_float4(acc[i][0], acc[i][1], acc[i][2], acc[i][3]);
        *(float4*)&Out[(size_t)(row0 + tm + i) * D_ + col0 + tn] = v;
    }
}

// ---------------- K2: Sc = scale * Q Kᵀ, causal lower-tri tiles, diag masked ----------------
__global__ __launch_bounds__(256) void scores_gemm(
    const float* __restrict__ Q, const float* __restrict__ Kp, float* __restrict__ Sc)
{
    const int kt = blockIdx.x, qt = blockIdx.y, b = blockIdx.z;
    if (kt > qt) return;   // strictly above diagonal: never written, never read
    const float* A  = Q  + (size_t)b * S_ * D_;
    const float* Bm = Kp + (size_t)b * S_ * D_;
    float* Sb = Sc + (size_t)b * S_ * S_;
    const int q0 = qt * BM, k0c = kt * BN;
    __shared__ float As[BK][BM];
    __shared__ float Bs[BK][BN];
    const int tid = threadIdx.x;
    const int ar = tid >> 2, ac4 = (tid & 3) << 2;
    const int tm = (tid >> 4) << 2, tn = (tid & 15) << 2;
    float acc[4][4] = {};
    for (int d0 = 0; d0 < D_; d0 += BK) {
        float4 av = *(const float4*)&A [(size_t)(q0  + ar) * D_ + d0 + ac4];
        float4 bv = *(const float4*)&Bm[(size_t)(k0c + ar) * D_ + d0 + ac4];
        __syncthreads();
        As[ac4+0][ar] = av.x; As[ac4+1][ar] = av.y; As[ac4+2][ar] = av.z; As[ac4+3][ar] = av.w;
        Bs[ac4+0][ar] = bv.x; Bs[ac4+1][ar] = bv.y; Bs[ac4+2][ar] = bv.z; Bs[ac4+3][ar] = bv.w;
        __syncthreads();
#pragma unroll
        for (int kk = 0; kk < BK; ++kk) {
            float a[4], bvv[4];
            *(float4*)a   = *(const float4*)&As[kk][tm];
            *(float4*)bvv = *(const float4*)&Bs[kk][tn];
#pragma unroll
            for (int i = 0; i < 4; ++i)
#pragma unroll
                for (int j = 0; j < 4; ++j) acc[i][j] = fmaf(a[i], bvv[j], acc[i][j]);
        }
    }
#pragma unroll
    for (int i = 0; i < 4; ++i) {
        const int qrow = q0 + tm + i;
        float4 v;
        v.x = (k0c + tn + 0 <= qrow) ? acc[i][0] * SCALE : NEGINF;
        v.y = (k0c + tn + 1 <= qrow) ? acc[i][1] * SCALE : NEGINF;
        v.z = (k0c + tn + 2 <= qrow) ? acc[i][2] * SCALE : NEGINF;
        v.w = (k0c + tn + 3 <= qrow) ? acc[i][3] * SCALE : NEGINF;
        *(float4*)&Sb[(size_t)qrow * S_ + k0c + tn] = v;
    }
}

// ---------------- K3: in-place row softmax over the written (causal) span ----------------
__global__ __launch_bounds__(256) void softmax_rows(float* __restrict__ Sc)
{
    const int row = blockIdx.x;          // 0..N_-1
    const int b = row >> 11, q = row & (S_ - 1);
    const int L = ((q >> 6) + 1) << 6;   // written span: full tiles through the diagonal
    float* rowp = Sc + ((size_t)b * S_ + q) * S_;
    __shared__ float buf[S_];
    __shared__ float red[4];
    __shared__ float bcast;
    const int tid = threadIdx.x;

    float lmax = -3.4e38f;
    for (int i = tid << 2; i < L; i += 1024) {
        float4 v = *(const float4*)&rowp[i];
        *(float4*)&buf[i] = v;
        lmax = fmaxf(fmaxf(fmaxf(v.x, v.y), fmaxf(v.z, v.w)), lmax);
    }
    for (int off = 32; off; off >>= 1) lmax = fmaxf(lmax, __shfl_down(lmax, off, 64));
    if ((tid & 63) == 0) red[tid >> 6] = lmax;
    __syncthreads();
    if (tid == 0) bcast = fmaxf(fmaxf(red[0], red[1]), fmaxf(red[2], red[3]));
    __syncthreads();
    const float m = bcast;

    float lsum = 0.f;
    for (int i = tid << 2; i < L; i += 1024) {
        float4 v = *(const float4*)&buf[i];
        v.x = __expf(v.x - m); v.y = __expf(v.y - m);
        v.z = __expf(v.z - m); v.w = __expf(v.w - m);
        *(float4*)&buf[i] = v;
        lsum += v.x + v.y + v.z + v.w;
    }
    for (int off = 32; off; off >>= 1) lsum += __shfl_down(lsum, off, 64);
    if ((tid & 63) == 0) red[tid >> 6] = lsum;
    __syncthreads();
    if (tid == 0) bcast = red[0] + red[1] + red[2] + red[3];
    __syncthreads();
    const float inv = 1.0f / bcast;

    for (int i = tid << 2; i < L; i += 1024) {
        float4 v = *(const float4*)&buf[i];
        v.x *= inv; v.y *= inv; v.z *= inv; v.w *= inv;
        *(float4*)&rowp[i] = v;
    }
}

// ---------------- K4: O = P V (NN GEMM, K-extent limited by causal span) ----------------
__global__ __launch_bounds__(256) void pv_gemm(
    const float* __restrict__ Sc, const float* __restrict__ Vp, float* __restrict__ O)
{
    const int et = blockIdx.x, qt = blockIdx.y, b = blockIdx.z;
    const float* P  = Sc + (size_t)b * S_ * S_;
    const float* Bm = Vp + (size_t)b * S_ * D_;
    const int q0 = qt * BM, e0 = et * BN;
    const int Kext = (qt + 1) * BM;      // only tiles through the diagonal are nonzero
    __shared__ float As[BK][BM];
    __shared__ float Bs[BK][BN];
    const int tid = threadIdx.x;
    const int ar  = tid >> 2,  ac4 = (tid & 3)  << 2;
    const int bkr = tid >> 4,  bc4 = (tid & 15) << 2;
    const int tm  = (tid >> 4) << 2, tn = (tid & 15) << 2;
    float acc[4][4] = {};
    for (int k0 = 0; k0 < Kext; k0 += BK) {
        float4 av = *(const float4*)&P [(size_t)(q0 + ar) * S_ + k0 + ac4];
        float4 bv = *(const float4*)&Bm[(size_t)(k0 + bkr) * D_ + e0 + bc4];
        __syncthreads();
        As[ac4+0][ar] = av.x; As[ac4+1][ar] = av.y; As[ac4+2][ar] = av.z; As[ac4+3][ar] = av.w;
        *(float4*)&Bs[bkr][bc4] = bv;
        __syncthreads();
#pragma unroll
        for (int kk = 0; kk < BK; ++kk) {
            float a[4], bvv[4];
            *(float4*)a   = *(const float4*)&As[kk][tm];
            *(float4*)bvv = *(const float4*)&Bs[kk][tn];
#pragma unroll
            for (int i = 0; i < 4; ++i)
#pragma unroll
                for (int j = 0; j < 4; ++j) acc[i][j] = fmaf(a[i], bvv[j], acc[i][j]);
        }
    }
#pragma unroll
    for (int i = 0; i < 4; ++i) {
        float4 v = make_float4(acc[i][0], acc[i][1], acc[i][2], acc[i][3]);
        *(float4*)&O[((size_t)b * S_ + q0 + tm + i) * D_ + e0 + tn] = v;
    }
}

extern "C" void kernel_launch(void* const* d_in, const int* in_sizes, int n_in,
                              void* d_out, int out_size, void* d_ws, size_t ws_size,
                              hipStream_t stream) {
    const float* x  = (const float*)d_in[0];
    const float* Wq = (const float*)d_in[1];
    const float* Wk = (const float*)d_in[2];
    const float* Wv = (const float*)d_in[3];
    float* out = (float*)d_out;
    float* ws  = (float*)d_ws;

    float* Q  = ws;                                // 8192*1024 floats
    float* Kp = ws + (size_t)N_ * D_;
    float* Vp = ws + 2 * (size_t)N_ * D_;
    float* Sc = ws + 3 * (size_t)N_ * D_;          // 4*2048*2048 floats

    qkv_gemm   <<<dim3(D_/BN, N_/BM, 3),  256, 0, stream>>>(x, Wq, Wk, Wv, Q, Kp, Vp);
    scores_gemm<<<dim3(S_/BN, S_/BM, B_), 256, 0, stream>>>(Q, Kp, Sc);
    softmax_rows<<<dim3(N_),              256, 0, stream>>>(Sc);
    pv_gemm    <<<dim3(D_/BN, S_/BM, B_), 256, 0, stream>>>(Sc, Vp, out);
}

// Round 2
// 267.574 us; speedup vs baseline: 5.5674x; 5.5674x over previous
//
#include <hip/hip_runtime.h>

#define B_  4
#define S_  2048
#define D_  1024
#define N_  (B_*S_)
#define SCALE 0.03125f
#define NEGINF (-3.0e38f)

typedef unsigned short u16;
typedef __attribute__((ext_vector_type(8))) short short8;
typedef __attribute__((ext_vector_type(4))) float floatx4;

__device__ __forceinline__ u16 f2bf(float f) {           // RNE float->bf16
    unsigned int u = __float_as_uint(f);
    u += 0x7FFFu + ((u >> 16) & 1u);
    return (u16)(u >> 16);
}

__device__ __forceinline__ void gl_lds16(const void* g, void* l) {
    __builtin_amdgcn_global_load_lds(
        (const __attribute__((address_space(1))) unsigned int*)g,
        (__attribute__((address_space(3))) unsigned int*)l, 16, 0, 0);
}

// ---------------- casts / transposes ----------------
__global__ __launch_bounds__(256) void cast_x(const float* __restrict__ x, u16* __restrict__ xb) {
    size_t i = ((size_t)blockIdx.x * 256 + threadIdx.x) * 8;
    float4 a = *(const float4*)&x[i];
    float4 b = *(const float4*)&x[i + 4];
    short8 o;
    o[0]=f2bf(a.x); o[1]=f2bf(a.y); o[2]=f2bf(a.z); o[3]=f2bf(a.w);
    o[4]=f2bf(b.x); o[5]=f2bf(b.y); o[6]=f2bf(b.z); o[7]=f2bf(b.w);
    *(short8*)&xb[i] = o;
}

// W [K=1024][N=1024] fp32 -> Wt [N][K] bf16 (3 weights via z)
__global__ __launch_bounds__(256) void cast_wt(const float* __restrict__ Wq, const float* __restrict__ Wk,
                                               const float* __restrict__ Wv, u16* __restrict__ Wt) {
    const float* W = (blockIdx.z == 0) ? Wq : (blockIdx.z == 1) ? Wk : Wv;
    u16* Out = Wt + (size_t)blockIdx.z * D_ * D_;
    __shared__ float t[32][33];
    const int c = threadIdx.x & 31, r0 = threadIdx.x >> 5;
    const int i0 = blockIdx.y * 32, j0 = blockIdx.x * 32;
#pragma unroll
    for (int rr = 0; rr < 4; ++rr)
        t[r0 + rr * 8][c] = W[(size_t)(i0 + r0 + rr * 8) * D_ + j0 + c];
    __syncthreads();
#pragma unroll
    for (int rr = 0; rr < 4; ++rr)
        Out[(size_t)(j0 + r0 + rr * 8) * D_ + i0 + c] = f2bf(t[c][r0 + rr * 8]);
}

// V [B][S][D] bf16 -> Vt [B][D][S] bf16
__global__ __launch_bounds__(256) void transpose_v(const u16* __restrict__ V, u16* __restrict__ Vt) {
    const size_t bo = (size_t)blockIdx.z * S_ * D_;
    __shared__ u16 t[32][34];
    const int c = threadIdx.x & 31, r0 = threadIdx.x >> 5;
    const int d0 = blockIdx.x * 32, s0 = blockIdx.y * 32;
#pragma unroll
    for (int rr = 0; rr < 4; ++rr)
        t[r0 + rr * 8][c] = V[bo + (size_t)(s0 + r0 + rr * 8) * D_ + d0 + c];
    __syncthreads();
#pragma unroll
    for (int rr = 0; rr < 4; ++rr)
        Vt[bo + (size_t)(d0 + r0 + rr * 8) * S_ + s0 + c] = t[c][r0 + rr * 8];
}

// ---------------- MFMA NT-GEMM core: C[128x128] = A[128xK] * B[128xK]^T ----------------
// LDS tiles stored [row][64] with K-group XOR swizzle applied on the GLOBAL side
// (LDS dest must be wave-uniform + lane*16 for global_load_lds).
__device__ __forceinline__ void mfma_nt_loop(const u16* __restrict__ A, int lda,
                                             const u16* __restrict__ Bp, int ldb,
                                             int m0, int n0, int kext,
                                             u16* As, u16* Bs, floatx4 acc[4][4])
{
    const int tid  = threadIdx.x;
    const int lane = tid & 63;
    const int lr   = lane & 15, quad = lane >> 4;
    const int wm   = ((tid >> 6) & 1) * 64, wn = (tid >> 7) * 64;
    const int e    = tid * 8;

    for (int k0 = 0; k0 < kext; k0 += 64) {
        __syncthreads();
#pragma unroll
        for (int it = 0; it < 4; ++it) {
            int idx = it * 2048 + e;
            int row = idx >> 6;
            int cg  = (idx & 63) >> 3;
            int gc  = (cg ^ (row & 7)) << 3;   // swizzled global k-offset
            gl_lds16(&A [(size_t)(m0 + row) * lda + k0 + gc], &As[idx]);
            gl_lds16(&Bp[(size_t)(n0 + row) * ldb + k0 + gc], &Bs[idx]);
        }
        __syncthreads();
#pragma unroll
        for (int kk = 0; kk < 2; ++kk) {
            short8 af[4], bf[4];
            const int kg = kk * 4 + quad;
#pragma unroll
            for (int i = 0; i < 4; ++i) {
                int am = wm + i * 16 + lr;
                af[i] = *(const short8*)&As[am * 64 + ((kg ^ (am & 7)) << 3)];
                int bn = wn + i * 16 + lr;
                bf[i] = *(const short8*)&Bs[bn * 64 + ((kg ^ (bn & 7)) << 3)];
            }
#pragma unroll
            for (int i = 0; i < 4; ++i)
#pragma unroll
                for (int j = 0; j < 4; ++j)
                    acc[i][j] = __builtin_amdgcn_mfma_f32_16x16x32_bf16(af[i], bf[j], acc[i][j], 0, 0, 0);
        }
    }
}

// ---------------- K1: Q/K/V projection, bf16 out ----------------
__global__ __launch_bounds__(256) void qkv_mfma(const u16* __restrict__ xb, const u16* __restrict__ Wt,
                                                u16* __restrict__ Q, u16* __restrict__ K, u16* __restrict__ Vtmp)
{
    __shared__ u16 As[128 * 64], Bs[128 * 64];
    const int z = blockIdx.z;
    const u16* Bp = Wt + (size_t)z * D_ * D_;
    u16* Out = (z == 0) ? Q : (z == 1) ? K : Vtmp;
    const int m0 = blockIdx.y * 128, n0 = blockIdx.x * 128;
    floatx4 acc[4][4];
#pragma unroll
    for (int i = 0; i < 4; ++i)
#pragma unroll
        for (int j = 0; j < 4; ++j) acc[i][j] = (floatx4){0.f, 0.f, 0.f, 0.f};
    mfma_nt_loop(xb, D_, Bp, D_, m0, n0, D_, As, Bs, acc);

    const int lane = threadIdx.x & 63;
    const int lr = lane & 15, quad = lane >> 4;
    const int wm = ((threadIdx.x >> 6) & 1) * 64, wn = (threadIdx.x >> 7) * 64;
#pragma unroll
    for (int i = 0; i < 4; ++i)
#pragma unroll
        for (int j = 0; j < 4; ++j)
#pragma unroll
            for (int r = 0; r < 4; ++r)
                Out[(size_t)(m0 + wm + i * 16 + quad * 4 + r) * D_ + n0 + wn + j * 16 + lr] = f2bf(acc[i][j][r]);
}

// ---------------- K2: Sc = scale * Q K^T (causal tiles only), fp32 out ----------------
__global__ __launch_bounds__(256) void scores_mfma(const u16* __restrict__ Q, const u16* __restrict__ K,
                                                   float* __restrict__ Sc)
{
    const int kt = blockIdx.x, qt = blockIdx.y, b = blockIdx.z;
    if (kt > qt) return;
    __shared__ u16 As[128 * 64], Bs[128 * 64];
    const u16* A  = Q + (size_t)b * S_ * D_;
    const u16* Bp = K + (size_t)b * S_ * D_;
    float* Sb = Sc + (size_t)b * S_ * S_;
    const int m0 = qt * 128, n0 = kt * 128;
    floatx4 acc[4][4];
#pragma unroll
    for (int i = 0; i < 4; ++i)
#pragma unroll
        for (int j = 0; j < 4; ++j) acc[i][j] = (floatx4){0.f, 0.f, 0.f, 0.f};
    mfma_nt_loop(A, D_, Bp, D_, m0, n0, D_, As, Bs, acc);

    const int lane = threadIdx.x & 63;
    const int lr = lane & 15, quad = lane >> 4;
    const int wm = ((threadIdx.x >> 6) & 1) * 64, wn = (threadIdx.x >> 7) * 64;
#pragma unroll
    for (int i = 0; i < 4; ++i)
#pragma unroll
        for (int r = 0; r < 4; ++r) {
            const int grow = m0 + wm + i * 16 + quad * 4 + r;
#pragma unroll
            for (int j = 0; j < 4; ++j) {
                const int gcol = n0 + wn + j * 16 + lr;
                Sb[(size_t)grow * S_ + gcol] = (gcol <= grow) ? acc[i][j][r] * SCALE : NEGINF;
            }
        }
}

// ---------------- K3: row softmax, fp32 in -> bf16 P out ----------------
__global__ __launch_bounds__(256) void softmax_k(const float* __restrict__ Sc, u16* __restrict__ P)
{
    const int row = blockIdx.x;
    const int b = row >> 11, q = row & (S_ - 1);
    const int L = ((q >> 7) + 1) << 7;           // 128-granular causal span
    const float* rp = Sc + ((size_t)b * S_ + q) * S_;
    u16* pp = P + ((size_t)b * S_ + q) * S_;
    __shared__ float buf[S_];
    __shared__ float red[4];
    __shared__ float bc;
    const int tid = threadIdx.x;

    float lmax = -3.4e38f;
    for (int i = tid << 2; i < L; i += 1024) {
        float4 v = *(const float4*)&rp[i];
        *(float4*)&buf[i] = v;
        lmax = fmaxf(fmaxf(fmaxf(v.x, v.y), fmaxf(v.z, v.w)), lmax);
    }
    for (int off = 32; off; off >>= 1) lmax = fmaxf(lmax, __shfl_down(lmax, off, 64));
    if ((tid & 63) == 0) red[tid >> 6] = lmax;
    __syncthreads();
    if (tid == 0) bc = fmaxf(fmaxf(red[0], red[1]), fmaxf(red[2], red[3]));
    __syncthreads();
    const float m = bc;

    float lsum = 0.f;
    for (int i = tid << 2; i < L; i += 1024) {
        float4 v = *(const float4*)&buf[i];
        v.x = __expf(v.x - m); v.y = __expf(v.y - m);
        v.z = __expf(v.z - m); v.w = __expf(v.w - m);
        *(float4*)&buf[i] = v;
        lsum += v.x + v.y + v.z + v.w;
    }
    for (int off = 32; off; off >>= 1) lsum += __shfl_down(lsum, off, 64);
    if ((tid & 63) == 0) red[tid >> 6] = lsum;
    __syncthreads();
    if (tid == 0) bc = red[0] + red[1] + red[2] + red[3];
    __syncthreads();
    const float inv = 1.0f / bc;

    for (int i = tid << 2; i < L; i += 1024) {
        float4 v = *(const float4*)&buf[i];
        ushort4 o;
        o.x = f2bf(v.x * inv); o.y = f2bf(v.y * inv);
        o.z = f2bf(v.z * inv); o.w = f2bf(v.w * inv);
        *(ushort4*)&pp[i] = o;
    }
}

// ---------------- K4: O = P Vt^T (causal K-extent), fp32 out ----------------
__global__ __launch_bounds__(256) void pv_mfma(const u16* __restrict__ P, const u16* __restrict__ Vt,
                                               float* __restrict__ O)
{
    const int et = blockIdx.x, qt = blockIdx.y, b = blockIdx.z;
    __shared__ u16 As[128 * 64], Bs[128 * 64];
    const u16* A  = P  + (size_t)b * S_ * S_;
    const u16* Bp = Vt + (size_t)b * D_ * S_;
    const int m0 = qt * 128, n0 = et * 128;
    const int kext = (qt + 1) * 128;
    floatx4 acc[4][4];
#pragma unroll
    for (int i = 0; i < 4; ++i)
#pragma unroll
        for (int j = 0; j < 4; ++j) acc[i][j] = (floatx4){0.f, 0.f, 0.f, 0.f};
    mfma_nt_loop(A, S_, Bp, S_, m0, n0, kext, As, Bs, acc);

    const int lane = threadIdx.x & 63;
    const int lr = lane & 15, quad = lane >> 4;
    const int wm = ((threadIdx.x >> 6) & 1) * 64, wn = (threadIdx.x >> 7) * 64;
#pragma unroll
    for (int i = 0; i < 4; ++i)
#pragma unroll
        for (int r = 0; r < 4; ++r) {
            const int grow = m0 + wm + i * 16 + quad * 4 + r;
#pragma unroll
            for (int j = 0; j < 4; ++j)
                O[((size_t)b * S_ + grow) * D_ + n0 + wn + j * 16 + lr] = acc[i][j][r];
        }
}

extern "C" void kernel_launch(void* const* d_in, const int* in_sizes, int n_in,
                              void* d_out, int out_size, void* d_ws, size_t ws_size,
                              hipStream_t stream) {
    const float* x  = (const float*)d_in[0];
    const float* Wq = (const float*)d_in[1];
    const float* Wk = (const float*)d_in[2];
    const float* Wv = (const float*)d_in[3];
    float* out = (float*)d_out;
    char* w = (char*)d_ws;

    // layout (bytes): P bf16 [0,33.5M) aliases {xb [0,16.8M), Wt [16.8M,23.1M)} (dead after qkv)
    // Q [33.5M), K [50.3M), Vt [67.1M), Sc fp32 [83.9M,151M) aliases Vtmp [83.9M,100.7M)
    u16*  P    = (u16*)(w);
    u16*  xb   = (u16*)(w);
    u16*  Wt   = (u16*)(w + 16777216);
    u16*  Q    = (u16*)(w + 33554432);
    u16*  K    = (u16*)(w + 50331648);
    u16*  Vt   = (u16*)(w + 67108864);
    float* Sc  = (float*)(w + 83886080);
    u16*  Vtmp = (u16*)(w + 83886080);

    cast_x     <<<dim3(4096),        256, 0, stream>>>(x, xb);
    cast_wt    <<<dim3(32, 32, 3),   256, 0, stream>>>(Wq, Wk, Wv, Wt);
    qkv_mfma   <<<dim3(8, 64, 3),    256, 0, stream>>>(xb, Wt, Q, K, Vtmp);
    transpose_v<<<dim3(32, 64, B_),  256, 0, stream>>>(Vtmp, Vt);
    scores_mfma<<<dim3(16, 16, B_),  256, 0, stream>>>(Q, K, Sc);
    softmax_k  <<<dim3(N_),          256, 0, stream>>>(Sc, P);
    pv_mfma    <<<dim3(8, 16, B_),   256, 0, stream>>>(P, Vt, out);
}

// Round 5
// 264.788 us; speedup vs baseline: 5.6260x; 1.0105x over previous
//
#include <hip/hip_runtime.h>

#define B_  4
#define S_  2048
#define D_  1024
#define N_  (B_*S_)
#define SCALE 0.03125f
#define NEGINF (-3.0e38f)

typedef unsigned short u16;
typedef __attribute__((ext_vector_type(8))) short short8;
typedef __attribute__((ext_vector_type(4))) float floatx4;

__device__ __forceinline__ u16 f2bf(float f) {           // RNE float->bf16
    unsigned int u = __float_as_uint(f);
    u += 0x7FFFu + ((u >> 16) & 1u);
    return (u16)(u >> 16);
}
__device__ __forceinline__ float bf2f(u16 h) {
    return __uint_as_float((unsigned int)h << 16);
}

__device__ __forceinline__ void gl_lds16(const void* g, void* l) {
    __builtin_amdgcn_global_load_lds(
        (const __attribute__((address_space(1))) unsigned int*)g,
        (__attribute__((address_space(3))) unsigned int*)l, 16, 0, 0);
}

// ---------------- casts ----------------
__global__ __launch_bounds__(256) void cast_x(const float* __restrict__ x, u16* __restrict__ xb) {
    size_t i = ((size_t)blockIdx.x * 256 + threadIdx.x) * 8;
    float4 a = *(const float4*)&x[i];
    float4 b = *(const float4*)&x[i + 4];
    short8 o;
    o[0]=f2bf(a.x); o[1]=f2bf(a.y); o[2]=f2bf(a.z); o[3]=f2bf(a.w);
    o[4]=f2bf(b.x); o[5]=f2bf(b.y); o[6]=f2bf(b.z); o[7]=f2bf(b.w);
    *(short8*)&xb[i] = o;
}

// W [K][N] fp32 -> Wt [N][K] bf16 (3 weights via z)
__global__ __launch_bounds__(256) void cast_wt(const float* __restrict__ Wq, const float* __restrict__ Wk,
                                               const float* __restrict__ Wv, u16* __restrict__ Wt) {
    const float* W = (blockIdx.z == 0) ? Wq : (blockIdx.z == 1) ? Wk : Wv;
    u16* Out = Wt + (size_t)blockIdx.z * D_ * D_;
    __shared__ float t[32][33];
    const int c = threadIdx.x & 31, r0 = threadIdx.x >> 5;
    const int i0 = blockIdx.y * 32, j0 = blockIdx.x * 32;
#pragma unroll
    for (int rr = 0; rr < 4; ++rr)
        t[r0 + rr * 8][c] = W[(size_t)(i0 + r0 + rr * 8) * D_ + j0 + c];
    __syncthreads();
#pragma unroll
    for (int rr = 0; rr < 4; ++rr)
        Out[(size_t)(j0 + r0 + rr * 8) * D_ + i0 + c] = f2bf(t[c][r0 + rr * 8]);
}

// ---------------- MFMA 16x16x32 NT-GEMM core (round-2 verified) ----------------
// C[128x128] = A[128xK] * B[128xK]^T.  LDS tiles [row][64], 8-elem-group XOR
// swizzle applied on the GLOBAL side (LDS dest must be lane*16-contiguous).
__device__ __forceinline__ void mfma_nt_loop(const u16* __restrict__ A, int lda,
                                             const u16* __restrict__ Bp, int ldb,
                                             int m0, int n0, int kext,
                                             u16* As, u16* Bs, floatx4 acc[4][4])
{
    const int tid  = threadIdx.x;
    const int lane = tid & 63;
    const int lr   = lane & 15, quad = lane >> 4;
    const int wm   = ((tid >> 6) & 1) * 64, wn = (tid >> 7) * 64;
    const int e    = tid * 8;

    for (int k0 = 0; k0 < kext; k0 += 64) {
        __syncthreads();
#pragma unroll
        for (int it = 0; it < 4; ++it) {
            int idx = it * 2048 + e;
            int row = idx >> 6;
            int cg  = (idx & 63) >> 3;
            int gc  = (cg ^ (row & 7)) << 3;   // swizzled global k-offset
            gl_lds16(&A [(size_t)(m0 + row) * lda + k0 + gc], &As[idx]);
            gl_lds16(&Bp[(size_t)(n0 + row) * ldb + k0 + gc], &Bs[idx]);
        }
        __syncthreads();
#pragma unroll
        for (int kk = 0; kk < 2; ++kk) {
            short8 af[4], bf[4];
            const int kg = kk * 4 + quad;
#pragma unroll
            for (int i = 0; i < 4; ++i) {
                int am = wm + i * 16 + lr;
                af[i] = *(const short8*)&As[am * 64 + ((kg ^ (am & 7)) << 3)];
                int bn = wn + i * 16 + lr;
                bf[i] = *(const short8*)&Bs[bn * 64 + ((kg ^ (bn & 7)) << 3)];
            }
#pragma unroll
            for (int i = 0; i < 4; ++i)
#pragma unroll
                for (int j = 0; j < 4; ++j)
                    acc[i][j] = __builtin_amdgcn_mfma_f32_16x16x32_bf16(af[i], bf[j], acc[i][j], 0, 0, 0);
        }
    }
}

// C/D layout (verified): col = lane&15, row = (lane>>4)*4 + reg
#define EPI_VARS                                              \
    const int lane = threadIdx.x & 63;                        \
    const int lr = lane & 15, quad = lane >> 4;               \
    const int wm = ((threadIdx.x >> 6) & 1) * 64, wn = (threadIdx.x >> 7) * 64;

// ---------------- K1: Q/K/V projection; z==2 writes V transposed via LDS ----------------
__global__ __launch_bounds__(256) void qkv_mfma(const u16* __restrict__ xb, const u16* __restrict__ Wt,
                                                u16* __restrict__ Q, u16* __restrict__ K, u16* __restrict__ Vt)
{
    __shared__ u16 sh[17408];          // staging: As=sh[0..8191], Bs=sh[8192..16383]; z==2 reuses as 128x136
    u16* As = sh;
    u16* Bs = sh + 8192;
    const int z = blockIdx.z;
    const u16* Bp = Wt + (size_t)z * D_ * D_;
    const int m0 = blockIdx.y * 128, n0 = blockIdx.x * 128;
    floatx4 acc[4][4];
#pragma unroll
    for (int i = 0; i < 4; ++i)
#pragma unroll
        for (int j = 0; j < 4; ++j) acc[i][j] = (floatx4){0.f, 0.f, 0.f, 0.f};
    mfma_nt_loop(xb, D_, Bp, D_, m0, n0, D_, As, Bs, acc);

    EPI_VARS
    if (z < 2) {
        u16* Out = (z == 0) ? Q : K;
#pragma unroll
        for (int i = 0; i < 4; ++i)
#pragma unroll
            for (int j = 0; j < 4; ++j)
#pragma unroll
                for (int r = 0; r < 4; ++r)
                    Out[(size_t)(m0 + wm + i * 16 + quad * 4 + r) * D_ + n0 + wn + j * 16 + lr] = f2bf(acc[i][j][r]);
    } else {
        // V-transpose epilogue. m0 is a flattened B*S row: split into (batch, s0)
        // — Vt layout is [B][D][S]. (r4 bug: wrote (n0+el)*S_ + m0 which collides
        // across batches; 128 | 2048 so a tile never straddles batches.)
        const int bb = m0 >> 11;           // m0 / 2048
        const int s0 = m0 & (S_ - 1);
        u16* Vb = Vt + (size_t)bb * D_ * S_;
        __syncthreads();
#pragma unroll
        for (int i = 0; i < 4; ++i)
#pragma unroll
            for (int j = 0; j < 4; ++j) {
                const int col = wn + j * 16 + lr;              // e within tile
                const int rowb = wm + i * 16 + quad * 4;       // s within tile (4 contiguous)
                ushort4 o;
                o.x = f2bf(acc[i][j][0]); o.y = f2bf(acc[i][j][1]);
                o.z = f2bf(acc[i][j][2]); o.w = f2bf(acc[i][j][3]);
                *(ushort4*)&sh[col * 136 + rowb] = o;          // pad 136 keeps 8B/16B alignment
            }
        __syncthreads();
#pragma unroll
        for (int c = 0; c < 8; ++c) {
            int linear = c * 2048 + threadIdx.x * 8;
            int el = linear >> 7, sl = linear & 127;
            *(short8*)&Vb[(size_t)(n0 + el) * S_ + s0 + sl] = *(const short8*)&sh[el * 136 + sl];
        }
    }
}

// ---------------- K2: Sc = bf16(scale * Q K^T), packed causal triangle ----------------
__global__ __launch_bounds__(256) void scores_mfma(const u16* __restrict__ Q, const u16* __restrict__ K,
                                                   u16* __restrict__ Sc)
{
    const int t = blockIdx.x, b = blockIdx.z;
    int qt = (int)((sqrtf(8.0f * t + 1.0f) - 1.0f) * 0.5f);
    while ((qt + 1) * (qt + 2) / 2 <= t) ++qt;
    while (qt * (qt + 1) / 2 > t) --qt;
    const int kt = t - qt * (qt + 1) / 2;

    __shared__ u16 As[128 * 64], Bs[128 * 64];
    const u16* A  = Q + (size_t)b * S_ * D_;
    const u16* Bp = K + (size_t)b * S_ * D_;
    u16* Sb = Sc + (size_t)b * S_ * S_;
    const int m0 = qt * 128, n0 = kt * 128;
    floatx4 acc[4][4];
#pragma unroll
    for (int i = 0; i < 4; ++i)
#pragma unroll
        for (int j = 0; j < 4; ++j) acc[i][j] = (floatx4){0.f, 0.f, 0.f, 0.f};
    mfma_nt_loop(A, D_, Bp, D_, m0, n0, D_, As, Bs, acc);

    EPI_VARS
#pragma unroll
    for (int i = 0; i < 4; ++i)
#pragma unroll
        for (int r = 0; r < 4; ++r) {
            const int grow = m0 + wm + i * 16 + quad * 4 + r;
#pragma unroll
            for (int j = 0; j < 4; ++j) {
                const int gcol = n0 + wn + j * 16 + lr;
                const float v = (gcol <= grow) ? acc[i][j][r] * SCALE : NEGINF;
                Sb[(size_t)grow * S_ + gcol] = f2bf(v);
            }
        }
}

// ---------------- K3: row softmax, bf16 in -> bf16 P out (register-resident) ----------------
__global__ __launch_bounds__(256) void softmax_k(const u16* __restrict__ Sc, u16* __restrict__ P)
{
    const int row = blockIdx.x;
    const int b = row >> 11, q = row & (S_ - 1);
    const int L = ((q >> 7) + 1) << 7;           // 128-granular causal span
    const u16* rp = Sc + ((size_t)b * S_ + q) * S_;
    u16* pp = P + ((size_t)b * S_ + q) * S_;
    __shared__ float red[4];
    __shared__ float bc;
    const int tid = threadIdx.x;
    const int i = tid << 3;
    const bool act = i < L;

    float f[8];
    float lmax = -3.4e38f;
    if (act) {
        short8 v = *(const short8*)&rp[i];
#pragma unroll
        for (int k = 0; k < 8; ++k) { f[k] = bf2f((u16)v[k]); lmax = fmaxf(lmax, f[k]); }
    }
    for (int off = 32; off; off >>= 1) lmax = fmaxf(lmax, __shfl_down(lmax, off, 64));
    if ((tid & 63) == 0) red[tid >> 6] = lmax;
    __syncthreads();
    if (tid == 0) bc = fmaxf(fmaxf(red[0], red[1]), fmaxf(red[2], red[3]));
    __syncthreads();
    const float m = bc;

    float lsum = 0.f;
    if (act) {
#pragma unroll
        for (int k = 0; k < 8; ++k) { f[k] = __expf(f[k] - m); lsum += f[k]; }
    }
    for (int off = 32; off; off >>= 1) lsum += __shfl_down(lsum, off, 64);
    if ((tid & 63) == 0) red[tid >> 6] = lsum;
    __syncthreads();
    if (tid == 0) bc = red[0] + red[1] + red[2] + red[3];
    __syncthreads();
    const float inv = 1.0f / bc;

    if (act) {
        short8 o;
#pragma unroll
        for (int k = 0; k < 8; ++k) o[k] = (short)f2bf(f[k] * inv);
        *(short8*)&pp[i] = o;
    }
}

// ---------------- K4: O = P Vt^T (causal K-extent), fp32 out ----------------
__global__ __launch_bounds__(256) void pv_mfma(const u16* __restrict__ P, const u16* __restrict__ Vt,
                                               float* __restrict__ O)
{
    const int et = blockIdx.x, qt = blockIdx.y, b = blockIdx.z;
    __shared__ u16 As[128 * 64], Bs[128 * 64];
    const u16* A  = P  + (size_t)b * S_ * S_;
    const u16* Bp = Vt + (size_t)b * D_ * S_;
    const int m0 = qt * 128, n0 = et * 128;
    const int kext = (qt + 1) * 128;
    floatx4 acc[4][4];
#pragma unroll
    for (int i = 0; i < 4; ++i)
#pragma unroll
        for (int j = 0; j < 4; ++j) acc[i][j] = (floatx4){0.f, 0.f, 0.f, 0.f};
    mfma_nt_loop(A, S_, Bp, S_, m0, n0, kext, As, Bs, acc);

    EPI_VARS
#pragma unroll
    for (int i = 0; i < 4; ++i)
#pragma unroll
        for (int r = 0; r < 4; ++r) {
            const int grow = m0 + wm + i * 16 + quad * 4 + r;
#pragma unroll
            for (int j = 0; j < 4; ++j)
                O[((size_t)b * S_ + grow) * D_ + n0 + wn + j * 16 + lr] = acc[i][j][r];
        }
}

extern "C" void kernel_launch(void* const* d_in, const int* in_sizes, int n_in,
                              void* d_out, int out_size, void* d_ws, size_t ws_size,
                              hipStream_t stream) {
    const float* x  = (const float*)d_in[0];
    const float* Wq = (const float*)d_in[1];
    const float* Wk = (const float*)d_in[2];
    const float* Wv = (const float*)d_in[3];
    float* out = (float*)d_out;
    char* w = (char*)d_ws;

    // bytes: P bf16 [0,33.5M) aliases {xb [0,16.8M), Wt [16.8M,23.1M)} (dead after qkv)
    // Q [33.5M), K [50.3M), Vt [67.1M), Sc bf16 [83.9M,117.4M)
    u16* P  = (u16*)(w);
    u16* xb = (u16*)(w);
    u16* Wt = (u16*)(w + 16777216);
    u16* Q  = (u16*)(w + 33554432);
    u16* K  = (u16*)(w + 50331648);
    u16* Vt = (u16*)(w + 67108864);
    u16* Sc = (u16*)(w + 83886080);

    cast_x     <<<dim3(4096),         256, 0, stream>>>(x, xb);
    cast_wt    <<<dim3(32, 32, 3),    256, 0, stream>>>(Wq, Wk, Wv, Wt);
    qkv_mfma   <<<dim3(8, 64, 3),     256, 0, stream>>>(xb, Wt, Q, K, Vt);
    scores_mfma<<<dim3(136, 1, B_),   256, 0, stream>>>(Q, K, Sc);
    softmax_k  <<<dim3(N_),           256, 0, stream>>>(Sc, P);
    pv_mfma    <<<dim3(8, 16, B_),    256, 0, stream>>>(P, Vt, out);
}